// Round 4
// baseline (138.354 us; speedup 1.0000x reference)
//
#include <hip/hip_runtime.h>
#include <hip/hip_bf16.h>

typedef __attribute__((ext_vector_type(8))) short bf16x8;
typedef __attribute__((ext_vector_type(4))) short bf16x4;
typedef __attribute__((ext_vector_type(4))) float f32x4;
typedef __attribute__((ext_vector_type(4))) unsigned u32x4;
typedef __attribute__((ext_vector_type(4))) int i32x4;

constexpr int Bn = 4, Hn = 16, S = 2048, D = 64;
constexpr int BQ = 128;   // q rows per block
constexpr float LOG2E = 1.44269504088896340736f;

__device__ __forceinline__ unsigned cvtpk(float lo, float hi) {
    unsigned r;
    asm("v_cvt_pk_bf16_f32 %0, %1, %2" : "=v"(r) : "v"(lo), "v"(hi));
    return r;
}

__device__ __forceinline__ f32x4 mfma16(bf16x4 a, bf16x4 b, f32x4 c) {
#if __has_builtin(__builtin_amdgcn_mfma_f32_16x16x16bf16_1k)
    return __builtin_amdgcn_mfma_f32_16x16x16bf16_1k(a, b, c, 0, 0, 0);
#else
    asm volatile("v_mfma_f32_16x16x16_bf16 %0, %1, %2, %0"
                 : "+v"(c) : "v"(a), "v"(b));
    return c;
#endif
}

// ---------------- kernel 1: mask compaction (per batch) ----------------
__global__ void compact_mask(const void* __restrict__ maskg,
                             int* __restrict__ idxp, int* __restrict__ Mg) {
    const int b = blockIdx.x, t = threadIdx.x;
    __shared__ int wsum[4];
    __shared__ int Msh;

    const unsigned* mu = (const unsigned*)maskg;
    bool is_bytes = false;
    #pragma unroll 8
    for (int i = 0; i < 64; ++i) is_bytes |= (mu[i] > 1u);

    int keep[8]; int cnt = 0;
    #pragma unroll
    for (int i = 0; i < 8; ++i) {
        const int key = t * 8 + i;
        int m;
        if (is_bytes) m = ((const unsigned char*)maskg)[b * S + key];
        else          m = ((const int*)maskg)[b * S + key];
        keep[i] = (m == 0);
        cnt += keep[i];
    }
    const int l = t & 63, w = t >> 6;
    int pre = cnt;
    #pragma unroll
    for (int d = 1; d < 64; d <<= 1) {
        int v = __shfl_up(pre, d, 64);
        if (l >= d) pre += v;
    }
    if (l == 63) wsum[w] = pre;
    __syncthreads();
    int base = 0;
    for (int i = 0; i < w; ++i) base += wsum[i];
    int offs = base + pre - cnt;
    #pragma unroll
    for (int i = 0; i < 8; ++i)
        if (keep[i]) idxp[b * S + (offs++)] = t * 8 + i;
    if (t == 255) Msh = base + pre;
    __syncthreads();
    const int M = Msh;
    for (int i = M + t; i < S; i += 256) idxp[b * S + i] = 0;   // pad
    if (M == 0)   // degenerate: uniform softmax; identity index, flag via sign
        for (int i = t; i < S; i += 256) idxp[b * S + i] = i;
    if (t == 0) Mg[b] = (M == 0) ? -1 : M;
}

// ------------- kernel 2: pack compacted K/V to bf16 workspace -------------
// K' layout: [bh][key][d]            (tile = 64 consecutive keys => contiguous 8KB)
// V' layout: [bh][tile][dv][key64]   (contiguous 8KB per tile, transposed)
__global__ void pack_kv(const float* __restrict__ Kg, const float* __restrict__ Vg,
                        const int* __restrict__ idxp, const int* __restrict__ Mg,
                        short* __restrict__ Kw, short* __restrict__ Vw) {
    const int bh = blockIdx.x, b = bh >> 4;
    const int ck0 = blockIdx.y * 256;
    const int t = threadIdx.x;
    const int Mraw = Mg[b];
    const int M = (Mraw < 0) ? S : Mraw;
    if (ck0 >= M) return;
    const int* idxb = idxp + b * S;
    const float* Kp = Kg + (size_t)bh * S * D;
    const float* Vp = Vg + (size_t)bh * S * D;

    // ---- K pack ----
    {
        const int dc = (t & 7) * 8;
        #pragma unroll
        for (int tile = 0; tile < 4; ++tile)
            #pragma unroll
            for (int it = 0; it < 2; ++it) {
                const int key = ck0 + tile * 64 + (t >> 3) + it * 32;
                u32x4 pk = u32x4{0u, 0u, 0u, 0u};
                if (key < M) {
                    const float* src = Kp + (size_t)idxb[key] * D + dc;
                    #pragma unroll
                    for (int jj = 0; jj < 4; ++jj)
                        pk[jj] = cvtpk(src[2 * jj], src[2 * jj + 1]);
                }
                *(u32x4*)(Kw + ((size_t)bh * S + key) * D + dc) = pk;
            }
    }
    // ---- V pack (transposed, tile-major) ----
    {
        const int dv = t & 63;
        const int kb = (t >> 6) * 16;
        #pragma unroll
        for (int tile = 0; tile < 4; ++tile) {
            const int tg = (ck0 >> 6) + tile;
            float f[16];
            #pragma unroll
            for (int i = 0; i < 16; ++i) {
                const int key = ck0 + tile * 64 + kb + i;
                float v = 0.f;
                if (key < M) {
                    int row = idxb[key];
                    row = __builtin_amdgcn_readfirstlane(row);
                    v = Vp[(size_t)row * D + dv];
                }
                f[i] = v;
            }
            u32x4 p0, p1;
            #pragma unroll
            for (int jj = 0; jj < 4; ++jj) {
                p0[jj] = cvtpk(f[2 * jj], f[2 * jj + 1]);
                p1[jj] = cvtpk(f[8 + 2 * jj], f[9 + 2 * jj]);
            }
            short* dst = Vw + (((size_t)bh * 32 + tg) * 64 + dv) * 64 + kb;
            *(u32x4*)dst = p0;
            *(u32x4*)(dst + 8) = p1;
        }
    }
}

// ------- kernel 3: pipelined attention over packed bf16 K'/V' -------
__global__ __launch_bounds__(256, 3) void attn_packed(
    const float* __restrict__ Qg, const short* __restrict__ Kw,
    const short* __restrict__ Vw, const int* __restrict__ idxp,
    const int* __restrict__ Mg, float* __restrict__ outg)
{
    __shared__ alignas(16) short Kt[2][64][72];
    __shared__ alignas(16) short Vt[2][64][72];
    __shared__ alignas(16) float dtab[2176];
    __shared__ alignas(16) int   idxs[2][64];

    const int bid  = blockIdx.x;
    const int lblk = ((bid & 7) << 7) | (bid >> 3);   // XCD swizzle (bijective)
    const int qt   = lblk & 15;
    const int bh   = lblk >> 4;
    const int b    = bh >> 4;
    const int q0   = qt * BQ;

    const float* Qp   = Qg + ((size_t)bh * S + q0) * D;
    const short* Ksrc = Kw + (size_t)bh * S * D;          // [key][d]
    const short* Vsrc = Vw + (size_t)bh * 32 * 64 * 64;   // [tile][dv][key]
    float*       Op   = outg + ((size_t)bh * S + q0) * D;
    const int*   idxb = idxp + b * S;

    const int t  = threadIdx.x;
    const int w  = t >> 6;
    const int l  = t & 63;
    const int lr = l & 15;
    const int lg = l >> 4;

    const int  Mraw    = Mg[b];
    const bool uniform = (Mraw < 0);
    const int  M       = uniform ? S : Mraw;
    const int  ntiles  = (M + 63) >> 6;

    // ---- issue tile-0 loads immediately (latency overlaps setup below) ----
    u32x4 kr0, kr1, vr0, vr1;
    int ir = 0;
    kr0 = *(const u32x4*)(Ksrc + t * 16);
    kr1 = *(const u32x4*)(Ksrc + t * 16 + 8);
    vr0 = *(const u32x4*)(Vsrc + t * 16);
    vr1 = *(const u32x4*)(Vsrc + t * 16 + 8);
    if (t < 64) ir = idxb[t];

    // ---- decay table (exact): dtab[i] = 2^(-CD2*(q0+i-2047)^2) ----
    const float CD2 = (2.0f / ((float)S * (float)S)) * LOG2E;
    for (int i = t; i < 2176; i += 256) {
        const float r = (float)(q0 + i - 2047);
        dtab[i] = __builtin_exp2f(-CD2 * r * r);
    }

    // ---- Q fragments (B-operand), scaled; zeroed in uniform mode ----
    const float qscale = uniform ? 0.0f : 0.125f * LOG2E;
    bf16x8 qf[2][2];
    #pragma unroll
    for (int rt = 0; rt < 2; ++rt) {
        const int row = w * 32 + rt * 16 + lr;
        #pragma unroll
        for (int g = 0; g < 2; ++g) {
            const float* src = Qp + row * D + g * 32 + lg * 8;
            union { unsigned u[4]; bf16x8 v; } cv;
            #pragma unroll
            for (int jj = 0; jj < 4; ++jj)
                cv.u[jj] = cvtpk(src[2 * jj] * qscale, src[2 * jj + 1] * qscale);
            qf[rt][g] = cv.v;
        }
    }

    f32x4 Oacc[2][4];
    #pragma unroll
    for (int rt = 0; rt < 2; ++rt)
        #pragma unroll
        for (int dt = 0; dt < 4; ++dt) Oacc[rt][dt] = f32x4{0.f, 0.f, 0.f, 0.f};
    float mrun[2] = {-1e30f, -1e30f};
    float lrun[2] = {0.f, 0.f};

    const int qrl2047 = w * 32 + lr + 2047;
    const int wr = t >> 2, wc = (t & 3) * 16;   // reg->LDS write coords

    // ---- prologue: write tile 0 into buf 0 ----
    *(u32x4*)&Kt[0][wr][wc]     = kr0;
    *(u32x4*)&Kt[0][wr][wc + 8] = kr1;
    *(u32x4*)&Vt[0][wr][wc]     = vr0;
    *(u32x4*)&Vt[0][wr][wc + 8] = vr1;
    if (t < 64) idxs[0][t] = ir;
    __syncthreads();

    int c = 0;
    for (int tt = 0; tt < ntiles; ++tt) {
        const int  rem      = M - tt * 64;
        const bool last     = (rem <= 64);
        const bool havenext = (tt + 1 < ntiles);

        // ---- issue next-tile loads (hidden under compute) ----
        if (havenext) {
            const short* kp = Ksrc + (size_t)(tt + 1) * 4096;
            const short* vp = Vsrc + (size_t)(tt + 1) * 4096;
            kr0 = *(const u32x4*)(kp + t * 16);
            kr1 = *(const u32x4*)(kp + t * 16 + 8);
            vr0 = *(const u32x4*)(vp + t * 16);
            vr1 = *(const u32x4*)(vp + t * 16 + 8);
            if (t < 64) ir = idxb[(tt + 1) * 64 + t];
        }

        // ---- compute tile tt from buf c ----
        bf16x8 kf[4][2];
        #pragma unroll
        for (int kt = 0; kt < 4; ++kt)
            #pragma unroll
            for (int g = 0; g < 2; ++g)
                kf[kt][g] = *(const bf16x8*)&Kt[c][kt * 16 + lr][g * 32 + lg * 8];

        bf16x4 Xb[2][4];
        #pragma unroll
        for (int rt = 0; rt < 2; ++rt) {
            f32x4 sc[4];
            __builtin_amdgcn_s_setprio(1);
            #pragma unroll
            for (int kt = 0; kt < 4; ++kt) {
                f32x4 acc = f32x4{0.f, 0.f, 0.f, 0.f};
                acc = __builtin_amdgcn_mfma_f32_16x16x32_bf16(kf[kt][0], qf[rt][0], acc, 0, 0, 0);
                acc = __builtin_amdgcn_mfma_f32_16x16x32_bf16(kf[kt][1], qf[rt][1], acc, 0, 0, 0);
                sc[kt] = acc;
            }
            __builtin_amdgcn_s_setprio(0);
            float mt = fmaxf(fmaxf(sc[0][0], sc[0][1]), fmaxf(sc[0][2], sc[0][3]));
            #pragma unroll
            for (int kt = 1; kt < 4; ++kt)
                mt = fmaxf(mt, fmaxf(fmaxf(sc[kt][0], sc[kt][1]), fmaxf(sc[kt][2], sc[kt][3])));
            mt = fmaxf(mt, __shfl_xor(mt, 16, 64));
            mt = fmaxf(mt, __shfl_xor(mt, 32, 64));
            if (!__all(mt <= mrun[rt] + 8.0f)) {   // defer-max
                const float mnew = fmaxf(mrun[rt], mt);
                const float rs = __builtin_exp2f(mrun[rt] - mnew);
                mrun[rt] = mnew;
                lrun[rt] *= rs;
                #pragma unroll
                for (int dt = 0; dt < 4; ++dt) Oacc[rt][dt] *= rs;
            }
            const float m  = mrun[rt];
            const int   qi = qrl2047 + rt * 16;
            float lp = 0.f;
            #pragma unroll
            for (int kt = 0; kt < 4; ++kt) {
                const i32x4 iv = *(const i32x4*)&idxs[c][kt * 16 + lg * 4];
                float p0 = __builtin_exp2f(sc[kt][0] - m);
                float p1 = __builtin_exp2f(sc[kt][1] - m);
                float p2 = __builtin_exp2f(sc[kt][2] - m);
                float p3 = __builtin_exp2f(sc[kt][3] - m);
                if (last) {
                    const int ck = kt * 16 + lg * 4;
                    p0 = (ck + 0 < rem) ? p0 : 0.f;
                    p1 = (ck + 1 < rem) ? p1 : 0.f;
                    p2 = (ck + 2 < rem) ? p2 : 0.f;
                    p3 = (ck + 3 < rem) ? p3 : 0.f;
                }
                lp += (p0 + p1) + (p2 + p3);
                const float d0 = dtab[qi - iv[0]];
                const float d1 = dtab[qi - iv[1]];
                const float d2 = dtab[qi - iv[2]];
                const float d3 = dtab[qi - iv[3]];
                union { unsigned u[2]; bf16x4 v; } cx;
                cx.u[0] = cvtpk(p0 * d0, p1 * d1);
                cx.u[1] = cvtpk(p2 * d2, p3 * d3);
                Xb[rt][kt] = cx.v;
            }
            lrun[rt] += lp;
        }

        // ---- PV via K=16 MFMA ----
        __builtin_amdgcn_s_setprio(1);
        #pragma unroll
        for (int kt = 0; kt < 4; ++kt) {
            bf16x4 vA[4];
            #pragma unroll
            for (int dt = 0; dt < 4; ++dt)
                vA[dt] = *(const bf16x4*)&Vt[c][dt * 16 + lr][kt * 16 + lg * 4];
            #pragma unroll
            for (int dt = 0; dt < 4; ++dt) {
                Oacc[0][dt] = mfma16(vA[dt], Xb[0][kt], Oacc[0][dt]);
                Oacc[1][dt] = mfma16(vA[dt], Xb[1][kt], Oacc[1][dt]);
            }
        }
        __builtin_amdgcn_s_setprio(0);

        // ---- write next tile into buf c^1, single barrier ----
        if (havenext) {
            *(u32x4*)&Kt[c ^ 1][wr][wc]     = kr0;
            *(u32x4*)&Kt[c ^ 1][wr][wc + 8] = kr1;
            *(u32x4*)&Vt[c ^ 1][wr][wc]     = vr0;
            *(u32x4*)&Vt[c ^ 1][wr][wc + 8] = vr1;
            if (t < 64) idxs[c ^ 1][t] = ir;
        }
        __syncthreads();
        c ^= 1;
    }

    // ---- epilogue ----
    #pragma unroll
    for (int rt = 0; rt < 2; ++rt) {
        float ls = lrun[rt];
        ls += __shfl_xor(ls, 16, 64);
        ls += __shfl_xor(ls, 32, 64);
        const float inv = 1.0f / ls;
        const int row = w * 32 + rt * 16 + lr;
        #pragma unroll
        for (int dt = 0; dt < 4; ++dt) {
            f32x4 o = Oacc[rt][dt];
            o[0] *= inv; o[1] *= inv; o[2] *= inv; o[3] *= inv;
            *(f32x4*)&Op[(size_t)row * D + dt * 16 + lg * 4] = o;
        }
    }
}

// ------- kernel 4: round-3 gather fallback (used if ws too small) -------
__global__ __launch_bounds__(256, 3) void attn_gather(
    const float* __restrict__ Qg, const float* __restrict__ Kg,
    const float* __restrict__ Vg, const int* __restrict__ idxp,
    const int* __restrict__ Mg, float* __restrict__ outg)
{
    __shared__ alignas(16) short Kt[64][72];
    __shared__ alignas(16) short Vt[64][72];
    __shared__ alignas(16) float dtab[2176];
    __shared__ alignas(16) int   idxs[64];

    const int blk = blockIdx.x;
    const int qt  = blk & 15;
    const int bh  = blk >> 4;
    const int b   = bh >> 4;
    const int q0  = qt * BQ;

    const float* Qp = Qg + ((size_t)bh * S + q0) * D;
    const float* Kp = Kg + (size_t)bh * S * D;
    const float* Vp = Vg + (size_t)bh * S * D;
    float*       Op = outg + ((size_t)bh * S + q0) * D;
    const int*   idxb = idxp + b * S;

    const int t  = threadIdx.x;
    const int w  = t >> 6;
    const int l  = t & 63;
    const int lr = l & 15;
    const int lg = l >> 4;

    const int  Mraw    = Mg[b];
    const bool uniform = (Mraw < 0);
    const int  M       = uniform ? S : Mraw;

    const float CD2 = (2.0f / ((float)S * (float)S)) * LOG2E;
    for (int i = t; i < 2176; i += 256) {
        const float r = (float)(q0 + i - 2047);
        dtab[i] = __builtin_exp2f(-CD2 * r * r);
    }

    const float qscale = uniform ? 0.0f : 0.125f * LOG2E;
    bf16x8 qf[2][2];
    #pragma unroll
    for (int rt = 0; rt < 2; ++rt) {
        const int row = w * 32 + rt * 16 + lr;
        #pragma unroll
        for (int g = 0; g < 2; ++g) {
            const float* src = Qp + row * D + g * 32 + lg * 8;
            union { unsigned u[4]; bf16x8 v; } cv;
            #pragma unroll
            for (int jj = 0; jj < 4; ++jj)
                cv.u[jj] = cvtpk(src[2 * jj] * qscale, src[2 * jj + 1] * qscale);
            qf[rt][g] = cv.v;
        }
    }

    f32x4 Oacc[2][4];
    #pragma unroll
    for (int rt = 0; rt < 2; ++rt)
        #pragma unroll
        for (int dt = 0; dt < 4; ++dt) Oacc[rt][dt] = f32x4{0.f, 0.f, 0.f, 0.f};
    float mrun[2] = {-1e30f, -1e30f};
    float lrun[2] = {0.f, 0.f};

    const int qrl2047 = w * 32 + lr + 2047;

    for (int kv = 0; kv < M; kv += 64) {
        const int  rem  = M - kv;
        const bool last = (rem <= 64);
        __syncthreads();
        {
            const int key = t >> 3;
            const int dc  = (t & 7) * 8;
            #pragma unroll
            for (int it = 0; it < 2; ++it) {
                const int row = idxb[kv + key + it * 32];
                const float* src = Kp + (size_t)row * D + dc;
                u32x4 pk;
                #pragma unroll
                for (int jj = 0; jj < 4; ++jj)
                    pk[jj] = cvtpk(src[2 * jj], src[2 * jj + 1]);
                *(u32x4*)&Kt[key + it * 32][dc] = pk;
            }
        }
        if (t < 64) idxs[t] = idxb[kv + t];
        {
            const int dv = t & 63;
            const int kb = (t >> 6) * 16;
            float f[16];
            #pragma unroll
            for (int i = 0; i < 16; ++i) {
                int row = idxb[kv + kb + i];
                row = __builtin_amdgcn_readfirstlane(row);
                f[i] = Vp[(size_t)row * D + dv];
            }
            u32x4 p0, p1;
            #pragma unroll
            for (int jj = 0; jj < 4; ++jj) {
                p0[jj] = cvtpk(f[2 * jj], f[2 * jj + 1]);
                p1[jj] = cvtpk(f[8 + 2 * jj], f[9 + 2 * jj]);
            }
            *(u32x4*)&Vt[dv][kb]     = p0;
            *(u32x4*)&Vt[dv][kb + 8] = p1;
        }
        __syncthreads();

        bf16x8 kf[4][2];
        #pragma unroll
        for (int kt = 0; kt < 4; ++kt)
            #pragma unroll
            for (int g = 0; g < 2; ++g)
                kf[kt][g] = *(const bf16x8*)&Kt[kt * 16 + lr][g * 32 + lg * 8];

        bf16x4 Xb[2][4];
        #pragma unroll
        for (int rt = 0; rt < 2; ++rt) {
            f32x4 sc[4];
            #pragma unroll
            for (int kt = 0; kt < 4; ++kt) {
                f32x4 acc = f32x4{0.f, 0.f, 0.f, 0.f};
                acc = __builtin_amdgcn_mfma_f32_16x16x32_bf16(kf[kt][0], qf[rt][0], acc, 0, 0, 0);
                acc = __builtin_amdgcn_mfma_f32_16x16x32_bf16(kf[kt][1], qf[rt][1], acc, 0, 0, 0);
                sc[kt] = acc;
            }
            float mt = fmaxf(fmaxf(sc[0][0], sc[0][1]), fmaxf(sc[0][2], sc[0][3]));
            #pragma unroll
            for (int kt = 1; kt < 4; ++kt)
                mt = fmaxf(mt, fmaxf(fmaxf(sc[kt][0], sc[kt][1]), fmaxf(sc[kt][2], sc[kt][3])));
            mt = fmaxf(mt, __shfl_xor(mt, 16, 64));
            mt = fmaxf(mt, __shfl_xor(mt, 32, 64));
            if (!__all(mt <= mrun[rt] + 8.0f)) {
                const float mnew = fmaxf(mrun[rt], mt);
                const float rs = __builtin_exp2f(mrun[rt] - mnew);
                mrun[rt] = mnew;
                lrun[rt] *= rs;
                #pragma unroll
                for (int dt = 0; dt < 4; ++dt) Oacc[rt][dt] *= rs;
            }
            const float m  = mrun[rt];
            const int   qi = qrl2047 + rt * 16;
            float lp = 0.f;
            #pragma unroll
            for (int kt = 0; kt < 4; ++kt) {
                const i32x4 iv = *(const i32x4*)&idxs[kt * 16 + lg * 4];
                float p0 = __builtin_exp2f(sc[kt][0] - m);
                float p1 = __builtin_exp2f(sc[kt][1] - m);
                float p2 = __builtin_exp2f(sc[kt][2] - m);
                float p3 = __builtin_exp2f(sc[kt][3] - m);
                if (last) {
                    const int ck = kt * 16 + lg * 4;
                    p0 = (ck + 0 < rem) ? p0 : 0.f;
                    p1 = (ck + 1 < rem) ? p1 : 0.f;
                    p2 = (ck + 2 < rem) ? p2 : 0.f;
                    p3 = (ck + 3 < rem) ? p3 : 0.f;
                }
                lp += (p0 + p1) + (p2 + p3);
                const float d0 = dtab[qi - iv[0]];
                const float d1 = dtab[qi - iv[1]];
                const float d2 = dtab[qi - iv[2]];
                const float d3 = dtab[qi - iv[3]];
                union { unsigned u[2]; bf16x4 v; } cx;
                cx.u[0] = cvtpk(p0 * d0, p1 * d1);
                cx.u[1] = cvtpk(p2 * d2, p3 * d3);
                Xb[rt][kt] = cx.v;
            }
            lrun[rt] += lp * 0.f + lp; // keep structure; compiler folds
        }

        #pragma unroll
        for (int kt = 0; kt < 4; ++kt) {
            bf16x4 vA[4];
            #pragma unroll
            for (int dt = 0; dt < 4; ++dt)
                vA[dt] = *(const bf16x4*)&Vt[dt * 16 + lr][kt * 16 + lg * 4];
            #pragma unroll
            for (int dt = 0; dt < 4; ++dt) {
                Oacc[0][dt] = mfma16(vA[dt], Xb[0][kt], Oacc[0][dt]);
                Oacc[1][dt] = mfma16(vA[dt], Xb[1][kt], Oacc[1][dt]);
            }
        }
    }

    #pragma unroll
    for (int rt = 0; rt < 2; ++rt) {
        float ls = lrun[rt];
        ls += __shfl_xor(ls, 16, 64);
        ls += __shfl_xor(ls, 32, 64);
        const float inv = 1.0f / ls;
        const int row = w * 32 + rt * 16 + lr;
        #pragma unroll
        for (int dt = 0; dt < 4; ++dt) {
            f32x4 o = Oacc[rt][dt];
            o[0] *= inv; o[1] *= inv; o[2] *= inv; o[3] *= inv;
            *(f32x4*)&Op[(size_t)row * D + dt * 16 + lg * 4] = o;
        }
    }
}

extern "C" void kernel_launch(void* const* d_in, const int* in_sizes, int n_in,
                              void* d_out, int out_size, void* d_ws, size_t ws_size,
                              hipStream_t stream) {
    const float* Q = (const float*)d_in[0];
    const float* K = (const float*)d_in[1];
    const float* V = (const float*)d_in[2];
    const void*  M = d_in[3];
    float* out = (float*)d_out;

    int* idxp = (int*)d_ws;                       // Bn*S ints
    int* Mg   = idxp + Bn * S;                    // Bn ints
    size_t base = (((size_t)(Bn * S + Bn) * 4) + 255) & ~(size_t)255;
    short* Kw = (short*)((char*)d_ws + base);     // Bn*Hn*S*D bf16
    short* Vw = Kw + (size_t)Bn * Hn * S * D;
    const size_t need = base + 2 * (size_t)Bn * Hn * S * D * sizeof(short);

    compact_mask<<<dim3(Bn), dim3(256), 0, stream>>>(M, idxp, Mg);
    const int nblk = Bn * Hn * (S / BQ);   // 1024
    if (ws_size >= need) {
        pack_kv<<<dim3(Bn * Hn, S / 256), dim3(256), 0, stream>>>(K, V, idxp, Mg, Kw, Vw);
        attn_packed<<<dim3(nblk), dim3(256), 0, stream>>>(Q, Kw, Vw, idxp, Mg, out);
    } else {
        attn_gather<<<dim3(nblk), dim3(256), 0, stream>>>(Q, K, V, idxp, Mg, out);
    }
}

// Round 5
// 132.634 us; speedup vs baseline: 1.0431x; 1.0431x over previous
//
#include <hip/hip_runtime.h>
#include <hip/hip_bf16.h>

typedef __attribute__((ext_vector_type(8))) short bf16x8;
typedef __attribute__((ext_vector_type(4))) short bf16x4;
typedef __attribute__((ext_vector_type(4))) float f32x4;
typedef __attribute__((ext_vector_type(4))) unsigned u32x4;
typedef __attribute__((ext_vector_type(4))) int i32x4;

constexpr int Bn = 4, Hn = 16, S = 2048, D = 64;
constexpr int BQ = 128;   // q rows per block
constexpr float LOG2E = 1.44269504088896340736f;

__device__ __forceinline__ unsigned cvtpk(float lo, float hi) {
    unsigned r;
    asm("v_cvt_pk_bf16_f32 %0, %1, %2" : "=v"(r) : "v"(lo), "v"(hi));
    return r;
}

__device__ __forceinline__ f32x4 mfma16(bf16x4 a, bf16x4 b, f32x4 c) {
#if __has_builtin(__builtin_amdgcn_mfma_f32_16x16x16bf16_1k)
    return __builtin_amdgcn_mfma_f32_16x16x16bf16_1k(a, b, c, 0, 0, 0);
#else
    asm volatile("v_mfma_f32_16x16x16_bf16 %0, %1, %2, %0"
                 : "+v"(c) : "v"(a), "v"(b));
    return c;
#endif
}

// ---------------- kernel 1: mask compaction (per batch) ----------------
__global__ void compact_mask(const void* __restrict__ maskg,
                             int* __restrict__ idxp, int* __restrict__ Mg) {
    const int b = blockIdx.x, t = threadIdx.x;
    __shared__ int wsum[4];
    __shared__ int Msh;

    const unsigned* mu = (const unsigned*)maskg;
    bool is_bytes = false;
    #pragma unroll 8
    for (int i = 0; i < 64; ++i) is_bytes |= (mu[i] > 1u);

    int keep[8]; int cnt = 0;
    #pragma unroll
    for (int i = 0; i < 8; ++i) {
        const int key = t * 8 + i;
        int m;
        if (is_bytes) m = ((const unsigned char*)maskg)[b * S + key];
        else          m = ((const int*)maskg)[b * S + key];
        keep[i] = (m == 0);
        cnt += keep[i];
    }
    const int l = t & 63, w = t >> 6;
    int pre = cnt;
    #pragma unroll
    for (int d = 1; d < 64; d <<= 1) {
        int v = __shfl_up(pre, d, 64);
        if (l >= d) pre += v;
    }
    if (l == 63) wsum[w] = pre;
    __syncthreads();
    int base = 0;
    for (int i = 0; i < w; ++i) base += wsum[i];
    int offs = base + pre - cnt;
    #pragma unroll
    for (int i = 0; i < 8; ++i)
        if (keep[i]) idxp[b * S + (offs++)] = t * 8 + i;
    if (t == 255) Msh = base + pre;
    __syncthreads();
    const int M = Msh;
    for (int i = M + t; i < S; i += 256) idxp[b * S + i] = 0;   // pad
    if (M == 0)   // degenerate: uniform softmax; identity index, flag via sign
        for (int i = t; i < S; i += 256) idxp[b * S + i] = i;
    if (t == 0) Mg[b] = (M == 0) ? -1 : M;
}

// ------------- kernel 2: pack compacted K/V to bf16 workspace -------------
// K' layout: [bh][key][d]            (tile = 64 consecutive keys => contiguous 8KB)
// V' layout: [bh][tile][dv][key64]   (contiguous 8KB per tile, transposed)
__global__ void pack_kv(const float* __restrict__ Kg, const float* __restrict__ Vg,
                        const int* __restrict__ idxp, const int* __restrict__ Mg,
                        short* __restrict__ Kw, short* __restrict__ Vw) {
    const int bh = blockIdx.x, b = bh >> 4;
    const int ck0 = blockIdx.y * 256;
    const int t = threadIdx.x;
    const int Mraw = Mg[b];
    const int M = (Mraw < 0) ? S : Mraw;
    if (ck0 >= M) return;
    const int* idxb = idxp + b * S;
    const float* Kp = Kg + (size_t)bh * S * D;
    const float* Vp = Vg + (size_t)bh * S * D;

    // ---- K pack ----
    {
        const int dc = (t & 7) * 8;
        #pragma unroll
        for (int tile = 0; tile < 4; ++tile)
            #pragma unroll
            for (int it = 0; it < 2; ++it) {
                const int key = ck0 + tile * 64 + (t >> 3) + it * 32;
                u32x4 pk = u32x4{0u, 0u, 0u, 0u};
                if (key < M) {
                    const float* src = Kp + (size_t)idxb[key] * D + dc;
                    #pragma unroll
                    for (int jj = 0; jj < 4; ++jj)
                        pk[jj] = cvtpk(src[2 * jj], src[2 * jj + 1]);
                }
                *(u32x4*)(Kw + ((size_t)bh * S + key) * D + dc) = pk;
            }
    }
    // ---- V pack (transposed, tile-major) ----
    {
        const int dv = t & 63;
        const int kb = (t >> 6) * 16;
        #pragma unroll
        for (int tile = 0; tile < 4; ++tile) {
            const int tg = (ck0 >> 6) + tile;
            float f[16];
            #pragma unroll
            for (int i = 0; i < 16; ++i) {
                const int key = ck0 + tile * 64 + kb + i;
                float v = 0.f;
                if (key < M) {
                    int row = idxb[key];
                    row = __builtin_amdgcn_readfirstlane(row);
                    v = Vp[(size_t)row * D + dv];
                }
                f[i] = v;
            }
            u32x4 p0, p1;
            #pragma unroll
            for (int jj = 0; jj < 4; ++jj) {
                p0[jj] = cvtpk(f[2 * jj], f[2 * jj + 1]);
                p1[jj] = cvtpk(f[8 + 2 * jj], f[9 + 2 * jj]);
            }
            short* dst = Vw + (((size_t)bh * 32 + tg) * 64 + dv) * 64 + kb;
            *(u32x4*)dst = p0;
            *(u32x4*)(dst + 8) = p1;
        }
    }
}

// ------- kernel 3: pipelined attention, fixed-max softmax, swizzled LDS -------
__global__ __launch_bounds__(256, 3) void attn_packed(
    const float* __restrict__ Qg, const short* __restrict__ Kw,
    const short* __restrict__ Vw, const int* __restrict__ idxp,
    const int* __restrict__ Mg, float* __restrict__ outg)
{
    // [2][64 rows][64 shorts]: row = 128B = 8 granules of 16B; granule XOR (row&7)
    __shared__ alignas(16) short Kt[2][64][64];
    __shared__ alignas(16) short Vt[2][64][64];
    __shared__ alignas(16) float dtab[2176];
    __shared__ alignas(16) int   idxs[2][64];

    const int bid  = blockIdx.x;
    const int lblk = ((bid & 7) << 7) | (bid >> 3);   // XCD swizzle (bijective)
    const int qt   = lblk & 15;
    const int bh   = lblk >> 4;
    const int b    = bh >> 4;
    const int q0   = qt * BQ;

    const float* Qp   = Qg + ((size_t)bh * S + q0) * D;
    const short* Ksrc = Kw + (size_t)bh * S * D;          // [key][d]
    const short* Vsrc = Vw + (size_t)bh * 32 * 64 * 64;   // [tile][dv][key]
    float*       Op   = outg + ((size_t)bh * S + q0) * D;
    const int*   idxb = idxp + b * S;

    const int t  = threadIdx.x;
    const int w  = t >> 6;
    const int l  = t & 63;
    const int lr = l & 15;
    const int lg = l >> 4;
    const int lx = lr & 7;            // row&7 for all fragment reads (row = *16 + lr)

    const int  Mraw    = Mg[b];
    const bool uniform = (Mraw < 0);
    const int  M       = uniform ? S : Mraw;
    const int  ntiles  = (M + 63) >> 6;

    // ---- issue tile-0 loads immediately ----
    u32x4 kr0, kr1, vr0, vr1;
    int ir = 0;
    kr0 = *(const u32x4*)(Ksrc + t * 16);
    kr1 = *(const u32x4*)(Ksrc + t * 16 + 8);
    vr0 = *(const u32x4*)(Vsrc + t * 16);
    vr1 = *(const u32x4*)(Vsrc + t * 16 + 8);
    if (t < 64) ir = idxb[t];

    // ---- decay table (exact): dtab[i] = 2^(-CD2*(q0+i-2047)^2) ----
    const float CD2 = (2.0f / ((float)S * (float)S)) * LOG2E;
    for (int i = t; i < 2176; i += 256) {
        const float r = (float)(q0 + i - 2047);
        dtab[i] = __builtin_exp2f(-CD2 * r * r);
    }

    // ---- Q fragments (B-operand), scaled; zeroed in uniform mode ----
    const float qscale = uniform ? 0.0f : 0.125f * LOG2E;
    bf16x8 qf[2][2];
    #pragma unroll
    for (int rt = 0; rt < 2; ++rt) {
        const int row = w * 32 + rt * 16 + lr;
        #pragma unroll
        for (int g = 0; g < 2; ++g) {
            const float* src = Qp + row * D + g * 32 + lg * 8;
            union { unsigned u[4]; bf16x8 v; } cv;
            #pragma unroll
            for (int jj = 0; jj < 4; ++jj)
                cv.u[jj] = cvtpk(src[2 * jj] * qscale, src[2 * jj + 1] * qscale);
            qf[rt][g] = cv.v;
        }
    }

    f32x4 Oacc[2][4];
    #pragma unroll
    for (int rt = 0; rt < 2; ++rt)
        #pragma unroll
        for (int dt = 0; dt < 4; ++dt) Oacc[rt][dt] = f32x4{0.f, 0.f, 0.f, 0.f};
    float lrun[2] = {0.f, 0.f};

    const int qrl2047 = w * 32 + lr + 2047;

    // staging write coords (swizzled): row = t>>2, granules 2(t&3), 2(t&3)+1
    const int srow = t >> 2;
    const int sb0  = srow * 128 + (((2 * (t & 3)) ^ (srow & 7)) << 4);

    // ---- prologue: write tile 0 into buf 0 (swizzled) ----
    {
        char* kd = (char*)&Kt[0][0][0];
        char* vd = (char*)&Vt[0][0][0];
        *(u32x4*)(kd + sb0)        = kr0;
        *(u32x4*)(kd + (sb0 ^ 16)) = kr1;
        *(u32x4*)(vd + sb0)        = vr0;
        *(u32x4*)(vd + (sb0 ^ 16)) = vr1;
        if (t < 64) idxs[0][t] = ir;
    }
    __syncthreads();

    int c = 0;
    for (int tt = 0; tt < ntiles; ++tt) {
        const int  rem      = M - tt * 64;
        const bool last     = (rem <= 64);
        const bool havenext = (tt + 1 < ntiles);

        // ---- issue next-tile loads (hidden under compute) ----
        if (havenext) {
            const short* kp = Ksrc + (size_t)(tt + 1) * 4096;
            const short* vp = Vsrc + (size_t)(tt + 1) * 4096;
            kr0 = *(const u32x4*)(kp + t * 16);
            kr1 = *(const u32x4*)(kp + t * 16 + 8);
            vr0 = *(const u32x4*)(vp + t * 16);
            vr1 = *(const u32x4*)(vp + t * 16 + 8);
            if (t < 64) ir = idxb[(tt + 1) * 64 + t];
        }

        const char* kbase = (const char*)&Kt[c][0][0];
        const char* vbase = (const char*)&Vt[c][0][0];

        // ---- K fragments (A-operand), swizzled reads ----
        bf16x8 kf[4][2];
        #pragma unroll
        for (int kt = 0; kt < 4; ++kt)
            #pragma unroll
            for (int g = 0; g < 2; ++g)
                kf[kt][g] = *(const bf16x8*)(kbase + (kt * 16 + lr) * 128
                                             + (((4 * g + lg) ^ lx) << 4));

        bf16x4 Xb[2][4];
        #pragma unroll
        for (int rt = 0; rt < 2; ++rt) {
            f32x4 sc[4];
            __builtin_amdgcn_s_setprio(1);
            #pragma unroll
            for (int kt = 0; kt < 4; ++kt) {
                f32x4 acc = f32x4{0.f, 0.f, 0.f, 0.f};
                acc = __builtin_amdgcn_mfma_f32_16x16x32_bf16(kf[kt][0], qf[rt][0], acc, 0, 0, 0);
                acc = __builtin_amdgcn_mfma_f32_16x16x32_bf16(kf[kt][1], qf[rt][1], acc, 0, 0, 0);
                sc[kt] = acc;
            }
            __builtin_amdgcn_s_setprio(0);
            // ---- fixed-max softmax: p = 2^(s-16); shift cancels in O/l ----
            const int qi = qrl2047 + rt * 16;
            float lp = 0.f;
            #pragma unroll
            for (int kt = 0; kt < 4; ++kt) {
                const i32x4 iv = *(const i32x4*)&idxs[c][kt * 16 + lg * 4];
                float p0 = __builtin_exp2f(sc[kt][0] - 16.0f);
                float p1 = __builtin_exp2f(sc[kt][1] - 16.0f);
                float p2 = __builtin_exp2f(sc[kt][2] - 16.0f);
                float p3 = __builtin_exp2f(sc[kt][3] - 16.0f);
                if (last) {   // zero padded keys (wave-uniform branch)
                    const int ck = kt * 16 + lg * 4;
                    p0 = (ck + 0 < rem) ? p0 : 0.f;
                    p1 = (ck + 1 < rem) ? p1 : 0.f;
                    p2 = (ck + 2 < rem) ? p2 : 0.f;
                    p3 = (ck + 3 < rem) ? p3 : 0.f;
                }
                lp += (p0 + p1) + (p2 + p3);
                const float d0 = dtab[qi - iv[0]];
                const float d1 = dtab[qi - iv[1]];
                const float d2 = dtab[qi - iv[2]];
                const float d3 = dtab[qi - iv[3]];
                union { unsigned u[2]; bf16x4 v; } cx;
                cx.u[0] = cvtpk(p0 * d0, p1 * d1);
                cx.u[1] = cvtpk(p2 * d2, p3 * d3);
                Xb[rt][kt] = cx.v;
            }
            lrun[rt] += lp;
        }

        // ---- PV via K=16 MFMA, swizzled V reads ----
        __builtin_amdgcn_s_setprio(1);
        #pragma unroll
        for (int kt = 0; kt < 4; ++kt) {
            bf16x4 vA[4];
            #pragma unroll
            for (int dt = 0; dt < 4; ++dt)
                vA[dt] = *(const bf16x4*)(vbase + (dt * 16 + lr) * 128
                          + ((((2 * kt + (lg >> 1)) ^ lx) << 4) | ((lg & 1) << 3)));
            #pragma unroll
            for (int dt = 0; dt < 4; ++dt) {
                Oacc[0][dt] = mfma16(vA[dt], Xb[0][kt], Oacc[0][dt]);
                Oacc[1][dt] = mfma16(vA[dt], Xb[1][kt], Oacc[1][dt]);
            }
        }
        __builtin_amdgcn_s_setprio(0);

        // ---- write next tile into buf c^1 (swizzled), single barrier ----
        if (havenext) {
            char* kd = (char*)&Kt[c ^ 1][0][0];
            char* vd = (char*)&Vt[c ^ 1][0][0];
            *(u32x4*)(kd + sb0)        = kr0;
            *(u32x4*)(kd + (sb0 ^ 16)) = kr1;
            *(u32x4*)(vd + sb0)        = vr0;
            *(u32x4*)(vd + (sb0 ^ 16)) = vr1;
            if (t < 64) idxs[c ^ 1][t] = ir;
        }
        __syncthreads();
        c ^= 1;
    }

    // ---- epilogue ----
    #pragma unroll
    for (int rt = 0; rt < 2; ++rt) {
        float ls = lrun[rt];
        ls += __shfl_xor(ls, 16, 64);
        ls += __shfl_xor(ls, 32, 64);
        const float inv = 1.0f / ls;
        const int row = w * 32 + rt * 16 + lr;
        #pragma unroll
        for (int dt = 0; dt < 4; ++dt) {
            f32x4 o = Oacc[rt][dt];
            o[0] *= inv; o[1] *= inv; o[2] *= inv; o[3] *= inv;
            *(f32x4*)&Op[(size_t)row * D + dt * 16 + lg * 4] = o;
        }
    }
}

// ------- kernel 4: round-3 gather fallback (used if ws too small) -------
__global__ __launch_bounds__(256, 3) void attn_gather(
    const float* __restrict__ Qg, const float* __restrict__ Kg,
    const float* __restrict__ Vg, const int* __restrict__ idxp,
    const int* __restrict__ Mg, float* __restrict__ outg)
{
    __shared__ alignas(16) short Kt[64][72];
    __shared__ alignas(16) short Vt[64][72];
    __shared__ alignas(16) float dtab[2176];
    __shared__ alignas(16) int   idxs[64];

    const int blk = blockIdx.x;
    const int qt  = blk & 15;
    const int bh  = blk >> 4;
    const int b   = bh >> 4;
    const int q0  = qt * BQ;

    const float* Qp = Qg + ((size_t)bh * S + q0) * D;
    const float* Kp = Kg + (size_t)bh * S * D;
    const float* Vp = Vg + (size_t)bh * S * D;
    float*       Op = outg + ((size_t)bh * S + q0) * D;
    const int*   idxb = idxp + b * S;

    const int t  = threadIdx.x;
    const int w  = t >> 6;
    const int l  = t & 63;
    const int lr = l & 15;
    const int lg = l >> 4;

    const int  Mraw    = Mg[b];
    const bool uniform = (Mraw < 0);
    const int  M       = uniform ? S : Mraw;

    const float CD2 = (2.0f / ((float)S * (float)S)) * LOG2E;
    for (int i = t; i < 2176; i += 256) {
        const float r = (float)(q0 + i - 2047);
        dtab[i] = __builtin_exp2f(-CD2 * r * r);
    }

    const float qscale = uniform ? 0.0f : 0.125f * LOG2E;
    bf16x8 qf[2][2];
    #pragma unroll
    for (int rt = 0; rt < 2; ++rt) {
        const int row = w * 32 + rt * 16 + lr;
        #pragma unroll
        for (int g = 0; g < 2; ++g) {
            const float* src = Qp + row * D + g * 32 + lg * 8;
            union { unsigned u[4]; bf16x8 v; } cv;
            #pragma unroll
            for (int jj = 0; jj < 4; ++jj)
                cv.u[jj] = cvtpk(src[2 * jj] * qscale, src[2 * jj + 1] * qscale);
            qf[rt][g] = cv.v;
        }
    }

    f32x4 Oacc[2][4];
    #pragma unroll
    for (int rt = 0; rt < 2; ++rt)
        #pragma unroll
        for (int dt = 0; dt < 4; ++dt) Oacc[rt][dt] = f32x4{0.f, 0.f, 0.f, 0.f};
    float lrun[2] = {0.f, 0.f};

    const int qrl2047 = w * 32 + lr + 2047;

    for (int kv = 0; kv < M; kv += 64) {
        const int  rem  = M - kv;
        const bool last = (rem <= 64);
        __syncthreads();
        {
            const int key = t >> 3;
            const int dc  = (t & 7) * 8;
            #pragma unroll
            for (int it = 0; it < 2; ++it) {
                const int row = idxb[kv + key + it * 32];
                const float* src = Kp + (size_t)row * D + dc;
                u32x4 pk;
                #pragma unroll
                for (int jj = 0; jj < 4; ++jj)
                    pk[jj] = cvtpk(src[2 * jj], src[2 * jj + 1]);
                *(u32x4*)&Kt[key + it * 32][dc] = pk;
            }
        }
        if (t < 64) idxs[t] = idxb[kv + t];
        {
            const int dv = t & 63;
            const int kb = (t >> 6) * 16;
            float f[16];
            #pragma unroll
            for (int i = 0; i < 16; ++i) {
                int row = idxb[kv + kb + i];
                row = __builtin_amdgcn_readfirstlane(row);
                f[i] = Vp[(size_t)row * D + dv];
            }
            u32x4 p0, p1;
            #pragma unroll
            for (int jj = 0; jj < 4; ++jj) {
                p0[jj] = cvtpk(f[2 * jj], f[2 * jj + 1]);
                p1[jj] = cvtpk(f[8 + 2 * jj], f[9 + 2 * jj]);
            }
            *(u32x4*)&Vt[dv][kb]     = p0;
            *(u32x4*)&Vt[dv][kb + 8] = p1;
        }
        __syncthreads();

        bf16x8 kf[4][2];
        #pragma unroll
        for (int kt = 0; kt < 4; ++kt)
            #pragma unroll
            for (int g = 0; g < 2; ++g)
                kf[kt][g] = *(const bf16x8*)&Kt[kt * 16 + lr][g * 32 + lg * 8];

        bf16x4 Xb[2][4];
        #pragma unroll
        for (int rt = 0; rt < 2; ++rt) {
            f32x4 sc[4];
            #pragma unroll
            for (int kt = 0; kt < 4; ++kt) {
                f32x4 acc = f32x4{0.f, 0.f, 0.f, 0.f};
                acc = __builtin_amdgcn_mfma_f32_16x16x32_bf16(kf[kt][0], qf[rt][0], acc, 0, 0, 0);
                acc = __builtin_amdgcn_mfma_f32_16x16x32_bf16(kf[kt][1], qf[rt][1], acc, 0, 0, 0);
                sc[kt] = acc;
            }
            const int qi = qrl2047 + rt * 16;
            float lp = 0.f;
            #pragma unroll
            for (int kt = 0; kt < 4; ++kt) {
                const i32x4 iv = *(const i32x4*)&idxs[kt * 16 + lg * 4];
                float p0 = __builtin_exp2f(sc[kt][0] - 16.0f);
                float p1 = __builtin_exp2f(sc[kt][1] - 16.0f);
                float p2 = __builtin_exp2f(sc[kt][2] - 16.0f);
                float p3 = __builtin_exp2f(sc[kt][3] - 16.0f);
                if (last) {
                    const int ck = kt * 16 + lg * 4;
                    p0 = (ck + 0 < rem) ? p0 : 0.f;
                    p1 = (ck + 1 < rem) ? p1 : 0.f;
                    p2 = (ck + 2 < rem) ? p2 : 0.f;
                    p3 = (ck + 3 < rem) ? p3 : 0.f;
                }
                lp += (p0 + p1) + (p2 + p3);
                const float d0 = dtab[qi - iv[0]];
                const float d1 = dtab[qi - iv[1]];
                const float d2 = dtab[qi - iv[2]];
                const float d3 = dtab[qi - iv[3]];
                union { unsigned u[2]; bf16x4 v; } cx;
                cx.u[0] = cvtpk(p0 * d0, p1 * d1);
                cx.u[1] = cvtpk(p2 * d2, p3 * d3);
                Xb[rt][kt] = cx.v;
            }
            lrun[rt] += lp;
        }

        #pragma unroll
        for (int kt = 0; kt < 4; ++kt) {
            bf16x4 vA[4];
            #pragma unroll
            for (int dt = 0; dt < 4; ++dt)
                vA[dt] = *(const bf16x4*)&Vt[dt * 16 + lr][kt * 16 + lg * 4];
            #pragma unroll
            for (int dt = 0; dt < 4; ++dt) {
                Oacc[0][dt] = mfma16(vA[dt], Xb[0][kt], Oacc[0][dt]);
                Oacc[1][dt] = mfma16(vA[dt], Xb[1][kt], Oacc[1][dt]);
            }
        }
    }

    #pragma unroll
    for (int rt = 0; rt < 2; ++rt) {
        float ls = lrun[rt];
        ls += __shfl_xor(ls, 16, 64);
        ls += __shfl_xor(ls, 32, 64);
        const float inv = 1.0f / ls;
        const int row = w * 32 + rt * 16 + lr;
        #pragma unroll
        for (int dt = 0; dt < 4; ++dt) {
            f32x4 o = Oacc[rt][dt];
            o[0] *= inv; o[1] *= inv; o[2] *= inv; o[3] *= inv;
            *(f32x4*)&Op[(size_t)row * D + dt * 16 + lg * 4] = o;
        }
    }
}

extern "C" void kernel_launch(void* const* d_in, const int* in_sizes, int n_in,
                              void* d_out, int out_size, void* d_ws, size_t ws_size,
                              hipStream_t stream) {
    const float* Q = (const float*)d_in[0];
    const float* K = (const float*)d_in[1];
    const float* V = (const float*)d_in[2];
    const void*  M = d_in[3];
    float* out = (float*)d_out;

    int* idxp = (int*)d_ws;                       // Bn*S ints
    int* Mg   = idxp + Bn * S;                    // Bn ints
    size_t base = (((size_t)(Bn * S + Bn) * 4) + 255) & ~(size_t)255;
    short* Kw = (short*)((char*)d_ws + base);     // Bn*Hn*S*D bf16
    short* Vw = Kw + (size_t)Bn * Hn * S * D;
    const size_t need = base + 2 * (size_t)Bn * Hn * S * D * sizeof(short);

    compact_mask<<<dim3(Bn), dim3(256), 0, stream>>>(M, idxp, Mg);
    const int nblk = Bn * Hn * (S / BQ);   // 1024
    if (ws_size >= need) {
        pack_kv<<<dim3(Bn * Hn, S / 256), dim3(256), 0, stream>>>(K, V, idxp, Mg, Kw, Vw);
        attn_packed<<<dim3(nblk), dim3(256), 0, stream>>>(Q, Kw, Vw, idxp, Mg, out);
    } else {
        attn_gather<<<dim3(nblk), dim3(256), 0, stream>>>(Q, K, V, idxp, Mg, out);
    }
}

// Round 6
// 119.731 us; speedup vs baseline: 1.1555x; 1.1078x over previous
//
#include <hip/hip_runtime.h>
#include <hip/hip_bf16.h>

typedef __attribute__((ext_vector_type(8))) short bf16x8;
typedef __attribute__((ext_vector_type(4))) short bf16x4;
typedef __attribute__((ext_vector_type(4))) float f32x4;
typedef __attribute__((ext_vector_type(4))) unsigned u32x4;
typedef __attribute__((ext_vector_type(4))) int i32x4;

constexpr int Bn = 4, Hn = 16, S = 2048, D = 64;
constexpr int BQ = 128;   // q rows per block
constexpr float LOG2E = 1.44269504088896340736f;

__device__ __forceinline__ unsigned cvtpk(float lo, float hi) {
    unsigned r;
    asm("v_cvt_pk_bf16_f32 %0, %1, %2" : "=v"(r) : "v"(lo), "v"(hi));
    return r;
}

__device__ __forceinline__ f32x4 mfma16(bf16x4 a, bf16x4 b, f32x4 c) {
#if __has_builtin(__builtin_amdgcn_mfma_f32_16x16x16bf16_1k)
    return __builtin_amdgcn_mfma_f32_16x16x16bf16_1k(a, b, c, 0, 0, 0);
#else
    asm volatile("v_mfma_f32_16x16x16_bf16 %0, %1, %2, %0"
                 : "+v"(c) : "v"(a), "v"(b));
    return c;
#endif
}

// ---------------- kernel 1: mask compaction (per batch) ----------------
__global__ void compact_mask(const void* __restrict__ maskg,
                             int* __restrict__ idxp, int* __restrict__ Mg) {
    const int b = blockIdx.x, t = threadIdx.x;
    __shared__ int wsum[4];
    __shared__ int Msh;

    const unsigned* mu = (const unsigned*)maskg;
    bool is_bytes = false;
    #pragma unroll 8
    for (int i = 0; i < 64; ++i) is_bytes |= (mu[i] > 1u);

    int keep[8]; int cnt = 0;
    #pragma unroll
    for (int i = 0; i < 8; ++i) {
        const int key = t * 8 + i;
        int m;
        if (is_bytes) m = ((const unsigned char*)maskg)[b * S + key];
        else          m = ((const int*)maskg)[b * S + key];
        keep[i] = (m == 0);
        cnt += keep[i];
    }
    const int l = t & 63, w = t >> 6;
    int pre = cnt;
    #pragma unroll
    for (int d = 1; d < 64; d <<= 1) {
        int v = __shfl_up(pre, d, 64);
        if (l >= d) pre += v;
    }
    if (l == 63) wsum[w] = pre;
    __syncthreads();
    int base = 0;
    for (int i = 0; i < w; ++i) base += wsum[i];
    int offs = base + pre - cnt;
    #pragma unroll
    for (int i = 0; i < 8; ++i)
        if (keep[i]) idxp[b * S + (offs++)] = t * 8 + i;
    if (t == 255) Msh = base + pre;
    __syncthreads();
    const int M = Msh;
    for (int i = M + t; i < S; i += 256) idxp[b * S + i] = 0;   // pad
    if (M == 0)   // degenerate: uniform softmax; identity index, flag via sign
        for (int i = t; i < S; i += 256) idxp[b * S + i] = i;
    if (t == 0) Mg[b] = (M == 0) ? -1 : M;
}

// ------------- kernel 2: pack compacted K/V to bf16 workspace -------------
// K' layout: [bh][key][d]            (tile = 64 consecutive keys => contiguous 8KB)
// V' layout: [bh][tile][dv][key64]   (contiguous 8KB per tile, transposed)
__global__ void pack_kv(const float* __restrict__ Kg, const float* __restrict__ Vg,
                        const int* __restrict__ idxp, const int* __restrict__ Mg,
                        short* __restrict__ Kw, short* __restrict__ Vw) {
    const int bh = blockIdx.x, b = bh >> 4;
    const int ck0 = blockIdx.y * 256;
    const int t = threadIdx.x;
    const int Mraw = Mg[b];
    const int M = (Mraw < 0) ? S : Mraw;
    if (ck0 >= M) return;
    const int* idxb = idxp + b * S;
    const float* Kp = Kg + (size_t)bh * S * D;
    const float* Vp = Vg + (size_t)bh * S * D;

    // ---- K pack ----
    {
        const int dc = (t & 7) * 8;
        #pragma unroll
        for (int tile = 0; tile < 4; ++tile)
            #pragma unroll
            for (int it = 0; it < 2; ++it) {
                const int key = ck0 + tile * 64 + (t >> 3) + it * 32;
                u32x4 pk = u32x4{0u, 0u, 0u, 0u};
                if (key < M) {
                    const float* src = Kp + (size_t)idxb[key] * D + dc;
                    #pragma unroll
                    for (int jj = 0; jj < 4; ++jj)
                        pk[jj] = cvtpk(src[2 * jj], src[2 * jj + 1]);
                }
                *(u32x4*)(Kw + ((size_t)bh * S + key) * D + dc) = pk;
            }
    }
    // ---- V pack (transposed, tile-major) ----
    {
        const int dv = t & 63;
        const int kb = (t >> 6) * 16;
        #pragma unroll
        for (int tile = 0; tile < 4; ++tile) {
            const int tg = (ck0 >> 6) + tile;
            float f[16];
            #pragma unroll
            for (int i = 0; i < 16; ++i) {
                const int key = ck0 + tile * 64 + kb + i;
                float v = 0.f;
                if (key < M) {
                    int row = idxb[key];
                    row = __builtin_amdgcn_readfirstlane(row);
                    v = Vp[(size_t)row * D + dv];
                }
                f[i] = v;
            }
            u32x4 p0, p1;
            #pragma unroll
            for (int jj = 0; jj < 4; ++jj) {
                p0[jj] = cvtpk(f[2 * jj], f[2 * jj + 1]);
                p1[jj] = cvtpk(f[8 + 2 * jj], f[9 + 2 * jj]);
            }
            short* dst = Vw + (((size_t)bh * 32 + tg) * 64 + dv) * 64 + kb;
            *(u32x4*)dst = p0;
            *(u32x4*)(dst + 8) = p1;
        }
    }
}

// ------- kernel 3: 8-wave (16 q-rows/wave) pipelined attention -------
__global__ __launch_bounds__(512, 4) void attn_packed(
    const float* __restrict__ Qg, const short* __restrict__ Kw,
    const short* __restrict__ Vw, const int* __restrict__ idxp,
    const int* __restrict__ Mg, float* __restrict__ outg)
{
    // [2][64 rows][64 shorts]: row = 128B = 8 granules of 16B; granule XOR (row&7)
    __shared__ alignas(16) short Kt[2][64][64];
    __shared__ alignas(16) short Vt[2][64][64];
    __shared__ alignas(16) float dtab[2176];
    __shared__ alignas(16) int   idxs[2][64];

    const int bid  = blockIdx.x;
    const int lblk = ((bid & 7) << 7) | (bid >> 3);   // XCD swizzle (bijective)
    const int qt   = lblk & 15;
    const int bh   = lblk >> 4;
    const int b    = bh >> 4;
    const int q0   = qt * BQ;

    const float* Qp   = Qg + ((size_t)bh * S + q0) * D;
    const short* Ksrc = Kw + (size_t)bh * S * D;          // [key][d]
    const short* Vsrc = Vw + (size_t)bh * 32 * 64 * 64;   // [tile][dv][key]
    float*       Op   = outg + ((size_t)bh * S + q0) * D;
    const int*   idxb = idxp + b * S;

    const int t  = threadIdx.x;
    const int w  = t >> 6;            // 8 waves, 16 q-rows each
    const int l  = t & 63;
    const int lr = l & 15;
    const int lg = l >> 4;
    const int lx = lr & 7;            // row&7 for fragment reads (row = *16 + lr)

    const int  Mraw    = Mg[b];
    const bool uniform = (Mraw < 0);
    const int  M       = uniform ? S : Mraw;
    const int  ntiles  = (M + 63) >> 6;

    // ---- issue tile-0 loads immediately (one b128 per thread per tensor) ----
    u32x4 kr, vr;
    int ir = 0;
    kr = *(const u32x4*)(Ksrc + t * 8);
    vr = *(const u32x4*)(Vsrc + t * 8);
    if (t < 64) ir = idxb[t];

    // ---- decay table (exact): dtab[i] = 2^(-CD2*(q0+i-2047)^2) ----
    const float CD2 = (2.0f / ((float)S * (float)S)) * LOG2E;
    for (int i = t; i < 2176; i += 512) {
        const float r = (float)(q0 + i - 2047);
        dtab[i] = __builtin_exp2f(-CD2 * r * r);
    }

    // ---- Q fragments (B-operand), scaled; zeroed in uniform mode ----
    const float qscale = uniform ? 0.0f : 0.125f * LOG2E;
    bf16x8 qf[2];
    {
        const int row = w * 16 + lr;
        #pragma unroll
        for (int g = 0; g < 2; ++g) {
            const float* src = Qp + row * D + g * 32 + lg * 8;
            union { unsigned u[4]; bf16x8 v; } cv;
            #pragma unroll
            for (int jj = 0; jj < 4; ++jj)
                cv.u[jj] = cvtpk(src[2 * jj] * qscale, src[2 * jj + 1] * qscale);
            qf[g] = cv.v;
        }
    }

    f32x4 Oacc[4];    // [dt]: col = q = lr, row = dv = dt*16+lg*4+reg
    #pragma unroll
    for (int dt = 0; dt < 4; ++dt) Oacc[dt] = f32x4{0.f, 0.f, 0.f, 0.f};
    float lrun = 0.f;

    const int qi = w * 16 + lr + 2047;

    // staging write coords (swizzled): thread t owns granule (t&7) of row (t>>3)
    const int srow = t >> 3;
    const int sb0  = srow * 128 + ((((t & 7)) ^ (srow & 7)) << 4);

    // ---- prologue: write tile 0 into buf 0 (swizzled) ----
    *(u32x4*)((char*)&Kt[0][0][0] + sb0) = kr;
    *(u32x4*)((char*)&Vt[0][0][0] + sb0) = vr;
    if (t < 64) idxs[0][t] = ir;
    __syncthreads();

    int c = 0;
    for (int tt = 0; tt < ntiles; ++tt) {
        const int  rem      = M - tt * 64;
        const bool last     = (rem <= 64);
        const bool havenext = (tt + 1 < ntiles);

        // ---- issue next-tile loads (hidden under compute) ----
        if (havenext) {
            kr = *(const u32x4*)(Ksrc + (size_t)(tt + 1) * 4096 + t * 8);
            vr = *(const u32x4*)(Vsrc + (size_t)(tt + 1) * 4096 + t * 8);
            if (t < 64) ir = idxb[(tt + 1) * 64 + t];
        }

        const char* kbase = (const char*)&Kt[c][0][0];
        const char* vbase = (const char*)&Vt[c][0][0];

        // ---- K fragments (A-operand), swizzled reads ----
        bf16x8 kf[4][2];
        #pragma unroll
        for (int kt = 0; kt < 4; ++kt)
            #pragma unroll
            for (int g = 0; g < 2; ++g)
                kf[kt][g] = *(const bf16x8*)(kbase + (kt * 16 + lr) * 128
                                             + (((4 * g + lg) ^ lx) << 4));

        // ---- swapped QK^T: C[ckey][q], col=q=lr, row=ckey=kt*16+lg*4+j ----
        f32x4 sc[4];
        __builtin_amdgcn_s_setprio(1);
        #pragma unroll
        for (int kt = 0; kt < 4; ++kt) {
            f32x4 acc = f32x4{0.f, 0.f, 0.f, 0.f};
            acc = __builtin_amdgcn_mfma_f32_16x16x32_bf16(kf[kt][0], qf[0], acc, 0, 0, 0);
            acc = __builtin_amdgcn_mfma_f32_16x16x32_bf16(kf[kt][1], qf[1], acc, 0, 0, 0);
            sc[kt] = acc;
        }
        __builtin_amdgcn_s_setprio(0);

        // ---- fixed-max softmax: p = 2^(s-16); shift cancels in O/l ----
        bf16x4 Xb[4];
        float lp = 0.f;
        #pragma unroll
        for (int kt = 0; kt < 4; ++kt) {
            const i32x4 iv = *(const i32x4*)&idxs[c][kt * 16 + lg * 4];
            float p0 = __builtin_exp2f(sc[kt][0] - 16.0f);
            float p1 = __builtin_exp2f(sc[kt][1] - 16.0f);
            float p2 = __builtin_exp2f(sc[kt][2] - 16.0f);
            float p3 = __builtin_exp2f(sc[kt][3] - 16.0f);
            if (last) {   // zero padded keys (wave-uniform branch)
                const int ck = kt * 16 + lg * 4;
                p0 = (ck + 0 < rem) ? p0 : 0.f;
                p1 = (ck + 1 < rem) ? p1 : 0.f;
                p2 = (ck + 2 < rem) ? p2 : 0.f;
                p3 = (ck + 3 < rem) ? p3 : 0.f;
            }
            lp += (p0 + p1) + (p2 + p3);
            const float d0 = dtab[qi - iv[0]];
            const float d1 = dtab[qi - iv[1]];
            const float d2 = dtab[qi - iv[2]];
            const float d3 = dtab[qi - iv[3]];
            union { unsigned u[2]; bf16x4 v; } cx;
            cx.u[0] = cvtpk(p0 * d0, p1 * d1);
            cx.u[1] = cvtpk(p2 * d2, p3 * d3);
            Xb[kt] = cx.v;
        }
        lrun += lp;

        // ---- PV via K=16 MFMA, swizzled V reads ----
        __builtin_amdgcn_s_setprio(1);
        #pragma unroll
        for (int kt = 0; kt < 4; ++kt) {
            bf16x4 vA[4];
            #pragma unroll
            for (int dt = 0; dt < 4; ++dt)
                vA[dt] = *(const bf16x4*)(vbase + (dt * 16 + lr) * 128
                          + ((((2 * kt + (lg >> 1)) ^ lx) << 4) | ((lg & 1) << 3)));
            #pragma unroll
            for (int dt = 0; dt < 4; ++dt)
                Oacc[dt] = mfma16(vA[dt], Xb[kt], Oacc[dt]);
        }
        __builtin_amdgcn_s_setprio(0);

        // ---- write next tile into buf c^1 (swizzled), single barrier ----
        if (havenext) {
            *(u32x4*)((char*)&Kt[c ^ 1][0][0] + sb0) = kr;
            *(u32x4*)((char*)&Vt[c ^ 1][0][0] + sb0) = vr;
            if (t < 64) idxs[c ^ 1][t] = ir;
        }
        __syncthreads();
        c ^= 1;
    }

    // ---- epilogue ----
    {
        float ls = lrun;
        ls += __shfl_xor(ls, 16, 64);
        ls += __shfl_xor(ls, 32, 64);
        const float inv = 1.0f / ls;
        const int row = w * 16 + lr;
        #pragma unroll
        for (int dt = 0; dt < 4; ++dt) {
            f32x4 o = Oacc[dt];
            o[0] *= inv; o[1] *= inv; o[2] *= inv; o[3] *= inv;
            *(f32x4*)&Op[(size_t)row * D + dt * 16 + lg * 4] = o;
        }
    }
}

// ------- kernel 4: round-5 gather fallback (used if ws too small) -------
__global__ __launch_bounds__(256, 3) void attn_gather(
    const float* __restrict__ Qg, const float* __restrict__ Kg,
    const float* __restrict__ Vg, const int* __restrict__ idxp,
    const int* __restrict__ Mg, float* __restrict__ outg)
{
    __shared__ alignas(16) short Kt[64][72];
    __shared__ alignas(16) short Vt[64][72];
    __shared__ alignas(16) float dtab[2176];
    __shared__ alignas(16) int   idxs[64];

    const int blk = blockIdx.x;
    const int qt  = blk & 15;
    const int bh  = blk >> 4;
    const int b   = bh >> 4;
    const int q0  = qt * BQ;

    const float* Qp = Qg + ((size_t)bh * S + q0) * D;
    const float* Kp = Kg + (size_t)bh * S * D;
    const float* Vp = Vg + (size_t)bh * S * D;
    float*       Op = outg + ((size_t)bh * S + q0) * D;
    const int*   idxb = idxp + b * S;

    const int t  = threadIdx.x;
    const int w  = t >> 6;
    const int l  = t & 63;
    const int lr = l & 15;
    const int lg = l >> 4;

    const int  Mraw    = Mg[b];
    const bool uniform = (Mraw < 0);
    const int  M       = uniform ? S : Mraw;

    const float CD2 = (2.0f / ((float)S * (float)S)) * LOG2E;
    for (int i = t; i < 2176; i += 256) {
        const float r = (float)(q0 + i - 2047);
        dtab[i] = __builtin_exp2f(-CD2 * r * r);
    }

    const float qscale = uniform ? 0.0f : 0.125f * LOG2E;
    bf16x8 qf[2][2];
    #pragma unroll
    for (int rt = 0; rt < 2; ++rt) {
        const int row = w * 32 + rt * 16 + lr;
        #pragma unroll
        for (int g = 0; g < 2; ++g) {
            const float* src = Qp + row * D + g * 32 + lg * 8;
            union { unsigned u[4]; bf16x8 v; } cv;
            #pragma unroll
            for (int jj = 0; jj < 4; ++jj)
                cv.u[jj] = cvtpk(src[2 * jj] * qscale, src[2 * jj + 1] * qscale);
            qf[rt][g] = cv.v;
        }
    }

    f32x4 Oacc[2][4];
    #pragma unroll
    for (int rt = 0; rt < 2; ++rt)
        #pragma unroll
        for (int dt = 0; dt < 4; ++dt) Oacc[rt][dt] = f32x4{0.f, 0.f, 0.f, 0.f};
    float lrun[2] = {0.f, 0.f};

    const int qrl2047 = w * 32 + lr + 2047;

    for (int kv = 0; kv < M; kv += 64) {
        const int  rem  = M - kv;
        const bool last = (rem <= 64);
        __syncthreads();
        {
            const int key = t >> 3;
            const int dc  = (t & 7) * 8;
            #pragma unroll
            for (int it = 0; it < 2; ++it) {
                const int row = idxb[kv + key + it * 32];
                const float* src = Kp + (size_t)row * D + dc;
                u32x4 pk;
                #pragma unroll
                for (int jj = 0; jj < 4; ++jj)
                    pk[jj] = cvtpk(src[2 * jj], src[2 * jj + 1]);
                *(u32x4*)&Kt[key + it * 32][dc] = pk;
            }
        }
        if (t < 64) idxs[t] = idxb[kv + t];
        {
            const int dv = t & 63;
            const int kb = (t >> 6) * 16;
            float f[16];
            #pragma unroll
            for (int i = 0; i < 16; ++i) {
                int row = idxb[kv + kb + i];
                row = __builtin_amdgcn_readfirstlane(row);
                f[i] = Vp[(size_t)row * D + dv];
            }
            u32x4 p0, p1;
            #pragma unroll
            for (int jj = 0; jj < 4; ++jj) {
                p0[jj] = cvtpk(f[2 * jj], f[2 * jj + 1]);
                p1[jj] = cvtpk(f[8 + 2 * jj], f[9 + 2 * jj]);
            }
            *(u32x4*)&Vt[dv][kb]     = p0;
            *(u32x4*)&Vt[dv][kb + 8] = p1;
        }
        __syncthreads();

        bf16x8 kf[4][2];
        #pragma unroll
        for (int kt = 0; kt < 4; ++kt)
            #pragma unroll
            for (int g = 0; g < 2; ++g)
                kf[kt][g] = *(const bf16x8*)&Kt[kt * 16 + lr][g * 32 + lg * 8];

        bf16x4 Xb[2][4];
        #pragma unroll
        for (int rt = 0; rt < 2; ++rt) {
            f32x4 sc[4];
            #pragma unroll
            for (int kt = 0; kt < 4; ++kt) {
                f32x4 acc = f32x4{0.f, 0.f, 0.f, 0.f};
                acc = __builtin_amdgcn_mfma_f32_16x16x32_bf16(kf[kt][0], qf[rt][0], acc, 0, 0, 0);
                acc = __builtin_amdgcn_mfma_f32_16x16x32_bf16(kf[kt][1], qf[rt][1], acc, 0, 0, 0);
                sc[kt] = acc;
            }
            const int qi = qrl2047 + rt * 16;
            float lp = 0.f;
            #pragma unroll
            for (int kt = 0; kt < 4; ++kt) {
                const i32x4 iv = *(const i32x4*)&idxs[kt * 16 + lg * 4];
                float p0 = __builtin_exp2f(sc[kt][0] - 16.0f);
                float p1 = __builtin_exp2f(sc[kt][1] - 16.0f);
                float p2 = __builtin_exp2f(sc[kt][2] - 16.0f);
                float p3 = __builtin_exp2f(sc[kt][3] - 16.0f);
                if (last) {
                    const int ck = kt * 16 + lg * 4;
                    p0 = (ck + 0 < rem) ? p0 : 0.f;
                    p1 = (ck + 1 < rem) ? p1 : 0.f;
                    p2 = (ck + 2 < rem) ? p2 : 0.f;
                    p3 = (ck + 3 < rem) ? p3 : 0.f;
                }
                lp += (p0 + p1) + (p2 + p3);
                const float d0 = dtab[qi - iv[0]];
                const float d1 = dtab[qi - iv[1]];
                const float d2 = dtab[qi - iv[2]];
                const float d3 = dtab[qi - iv[3]];
                union { unsigned u[2]; bf16x4 v; } cx;
                cx.u[0] = cvtpk(p0 * d0, p1 * d1);
                cx.u[1] = cvtpk(p2 * d2, p3 * d3);
                Xb[rt][kt] = cx.v;
            }
            lrun[rt] += lp;
        }

        #pragma unroll
        for (int kt = 0; kt < 4; ++kt) {
            bf16x4 vA[4];
            #pragma unroll
            for (int dt = 0; dt < 4; ++dt)
                vA[dt] = *(const bf16x4*)&Vt[dt * 16 + lr][kt * 16 + lg * 4];
            #pragma unroll
            for (int dt = 0; dt < 4; ++dt) {
                Oacc[0][dt] = mfma16(vA[dt], Xb[0][kt], Oacc[0][dt]);
                Oacc[1][dt] = mfma16(vA[dt], Xb[1][kt], Oacc[1][dt]);
            }
        }
    }

    #pragma unroll
    for (int rt = 0; rt < 2; ++rt) {
        float ls = lrun[rt];
        ls += __shfl_xor(ls, 16, 64);
        ls += __shfl_xor(ls, 32, 64);
        const float inv = 1.0f / ls;
        const int row = w * 32 + rt * 16 + lr;
        #pragma unroll
        for (int dt = 0; dt < 4; ++dt) {
            f32x4 o = Oacc[rt][dt];
            o[0] *= inv; o[1] *= inv; o[2] *= inv; o[3] *= inv;
            *(f32x4*)&Op[(size_t)row * D + dt * 16 + lg * 4] = o;
        }
    }
}

extern "C" void kernel_launch(void* const* d_in, const int* in_sizes, int n_in,
                              void* d_out, int out_size, void* d_ws, size_t ws_size,
                              hipStream_t stream) {
    const float* Q = (const float*)d_in[0];
    const float* K = (const float*)d_in[1];
    const float* V = (const float*)d_in[2];
    const void*  M = d_in[3];
    float* out = (float*)d_out;

    int* idxp = (int*)d_ws;                       // Bn*S ints
    int* Mg   = idxp + Bn * S;                    // Bn ints
    size_t base = (((size_t)(Bn * S + Bn) * 4) + 255) & ~(size_t)255;
    short* Kw = (short*)((char*)d_ws + base);     // Bn*Hn*S*D bf16
    short* Vw = Kw + (size_t)Bn * Hn * S * D;
    const size_t need = base + 2 * (size_t)Bn * Hn * S * D * sizeof(short);

    compact_mask<<<dim3(Bn), dim3(256), 0, stream>>>(M, idxp, Mg);
    const int nblk = Bn * Hn * (S / BQ);   // 1024
    if (ws_size >= need) {
        pack_kv<<<dim3(Bn * Hn, S / 256), dim3(256), 0, stream>>>(K, V, idxp, Mg, Kw, Vw);
        attn_packed<<<dim3(nblk), dim3(512), 0, stream>>>(Q, Kw, Vw, idxp, Mg, out);
    } else {
        attn_gather<<<dim3(nblk), dim3(256), 0, stream>>>(Q, K, V, idxp, Mg, out);
    }
}